// Round 13
// baseline (254.143 us; speedup 1.0000x reference)
//
#include <hip/hip_runtime.h>
#include <math.h>

typedef __bf16 bf16;
typedef bf16 bf16x2 __attribute__((ext_vector_type(2)));
typedef bf16 bf16x4 __attribute__((ext_vector_type(4)));
typedef bf16 bf16x8 __attribute__((ext_vector_type(8)));
typedef float f32x4 __attribute__((ext_vector_type(4)));

// Problem constants: B=64, S=512, D=1024, M=512, P=3
#define NROWS 32768   // B*S
#define DDIM 1024
#define MDIM 512

__device__ __forceinline__ float wave_reduce_sum(float v) {   // lane0 gets total
#pragma unroll
  for (int o = 32; o > 0; o >>= 1) v += __shfl_down(v, o, 64);
  return v;
}
__device__ __forceinline__ float wave_allreduce_sum(float v) { // all lanes get total
#pragma unroll
  for (int o = 32; o > 0; o >>= 1) v += __shfl_xor(v, o, 64);
  return v;
}

// async global->LDS, 16B per lane. LDS dest is wave-uniform base + lane*16.
__device__ __forceinline__ void load_lds16(const bf16* g, bf16* l) {
  __builtin_amdgcn_global_load_lds(
      (const __attribute__((address_space(1))) unsigned int*)g,
      (__attribute__((address_space(3))) unsigned int*)l, 16, 0, 0);
}
__device__ __forceinline__ void load_lds16f(const float* g, float* l) {
  __builtin_amdgcn_global_load_lds(
      (const __attribute__((address_space(1))) unsigned int*)g,
      (__attribute__((address_space(3))) unsigned int*)l, 16, 0, 0);
}

// ================= LayerNorm + aspect head: async-LDS pipelined ===========
// 1024 blocks x 4 waves x 8 rows/wave. Per-wave double-buffered LDS slots;
// global_load_lds keeps 8 loads in flight (zero VGPR cost) while the reduce
// chain of the previous row runs. No barriers: each wave owns its slots.
__global__ __launch_bounds__(256) void ln_kernel(
    const float* __restrict__ seq, const int* __restrict__ amask,
    const float* __restrict__ ga, const float* __restrict__ gb,
    const float* __restrict__ aw, const float* __restrict__ ab,
    bf16* __restrict__ xn, float* __restrict__ aspect_pred,
    float* __restrict__ loss_arr) {
  __shared__ __align__(16) float lbuf[4][2][1024];   // 32 KB
  const int lane = threadIdx.x & 63;
  const int wv = threadIdx.x >> 6;
  const int row0 = (blockIdx.x * 4 + wv) * 8;
  float* slot[2] = {&lbuf[wv][0][0], &lbuf[wv][1][0]};

  // prologue: stage row0 into slot0 (4 x 1KB async)
#pragma unroll
  for (int j = 0; j < 4; ++j)
    load_lds16f(&seq[(size_t)row0 * DDIM + j * 256 + lane * 4],
                slot[0] + j * 256);

  for (int i = 0; i < 8; ++i) {
    const int row = row0 + i;
    float* cur = slot[i & 1];
    float* nxt = slot[(i & 1) ^ 1];
    if (i < 7) {
#pragma unroll
      for (int j = 0; j < 4; ++j)
        load_lds16f(&seq[(size_t)(row + 1) * DDIM + j * 256 + lane * 4],
                    nxt + j * 256);
      // counted wait: 4 newest (row i+1) may remain in flight; row i landed
      asm volatile("s_waitcnt vmcnt(4)" ::: "memory");
    } else {
      asm volatile("s_waitcnt vmcnt(0)" ::: "memory");
    }
    __builtin_amdgcn_sched_barrier(0);
    f32x4 v[4];
#pragma unroll
    for (int j = 0; j < 4; ++j) v[j] = *(const f32x4*)&cur[j * 256 + lane * 4];
    float s = 0.0f, sq = 0.0f;
#pragma unroll
    for (int j = 0; j < 4; ++j) {
      s += v[j].x + v[j].y + v[j].z + v[j].w;
      sq += v[j].x * v[j].x + v[j].y * v[j].y + v[j].z * v[j].z + v[j].w * v[j].w;
    }
    s = wave_allreduce_sum(s);
    sq = wave_allreduce_sum(sq);
    float mean = s * (1.0f / 1024.0f);
    float var = (sq - 1024.0f * mean * mean) * (1.0f / 1023.0f);  // unbiased
    var = fmaxf(var, 0.0f);
    float inv = 1.0f / (sqrtf(var) + 1e-6f);
    float zp = 0.0f;
#pragma unroll
    for (int j = 0; j < 4; ++j) {
      int c = j * 256 + lane * 4;
      float4 a4 = *(const float4*)&ga[c];     // reused across blocks: cached
      float4 b4 = *(const float4*)&gb[c];
      float4 w4 = *(const float4*)&aw[c];
      float x0 = a4.x * (v[j].x - mean) * inv + b4.x;
      float x1 = a4.y * (v[j].y - mean) * inv + b4.y;
      float x2 = a4.z * (v[j].z - mean) * inv + b4.z;
      float x3 = a4.w * (v[j].w - mean) * inv + b4.w;
      bf16x4 o;
      o[0] = (bf16)x0; o[1] = (bf16)x1; o[2] = (bf16)x2; o[3] = (bf16)x3;
      __builtin_nontemporal_store(o, (bf16x4*)&xn[(size_t)row * DDIM + c]);
      zp += x0 * w4.x + x1 * w4.y + x2 * w4.z + x3 * w4.w;
    }
    zp = wave_reduce_sum(zp);
    if (lane == 0) {
      float z = zp + ab[0];
      aspect_pred[row] = 1.0f / (1.0f + expf(-z));
      float tgt = (float)amask[row];
      float bce = fmaxf(z, 0.0f) + log1pf(expf(-fabsf(z))) - z * tgt;
      loss_arr[row] = tgt * bce;
    }
  }
}

// ================= build_nbr | wcast ======================================
// grid: [0,8192) nbr (4 rows/block, wave-per-row); [8192,8448) wcast.
__global__ __launch_bounds__(256) void nbrw_kernel(
    const float* __restrict__ adj, const float* __restrict__ W0,
    const float* __restrict__ W1, const float* __restrict__ W2,
    unsigned short* __restrict__ nbr, int* __restrict__ cnt,
    float* __restrict__ denomv, bf16* __restrict__ W0T,
    bf16* __restrict__ W1T, bf16* __restrict__ W2T) {
  const int bid = blockIdx.x;
  const int tid = threadIdx.x;
  const int lane = tid & 63;
  const int wv = tid >> 6;

  if (bid < 8192) {
    // ---------------- neighbor-list build (one wave per row) --------------
    const int row = bid * 4 + wv;
    const float* ar = adj + (size_t)row * 512;
    unsigned short* nr = nbr + (size_t)row * 512;
    unsigned long long below = (1ull << lane) - 1ull;
    int base = 0;
#pragma unroll
    for (int t = 0; t < 2; ++t) {
      f32x4 v = __builtin_nontemporal_load((const f32x4*)&ar[t * 256 + lane * 4]);
      unsigned long long m0 = __ballot(v.x != 0.0f);
      unsigned long long m1 = __ballot(v.y != 0.0f);
      unsigned long long m2 = __ballot(v.z != 0.0f);
      unsigned long long m3 = __ballot(v.w != 0.0f);
      int c0 = __popcll(m0), c1 = __popcll(m1), c2 = __popcll(m2);
      int col = t * 256 + lane * 4;
      if (v.x != 0.0f) nr[base + __popcll(m0 & below)] = (unsigned short)(col + 0);
      if (v.y != 0.0f) nr[base + c0 + __popcll(m1 & below)] = (unsigned short)(col + 1);
      if (v.z != 0.0f) nr[base + c0 + c1 + __popcll(m2 & below)] = (unsigned short)(col + 2);
      if (v.w != 0.0f) nr[base + c0 + c1 + c2 + __popcll(m3 & below)] = (unsigned short)(col + 3);
      base += c0 + c1 + c2 + __popcll(m3);
    }
    if (lane == 0) { cnt[row] = base; denomv[row] = (float)base + 1.0f; }
  } else {
    // -------- weight cast+transpose via LDS 64x64 tiles -------------------
    __shared__ bf16 tld[64][72];   // +8 pad
    int wid = bid - 8192;
    const float* Wsrc; bf16* Wdst; int KK, NN, t0;
    if (wid < 128)      { Wsrc = W0; Wdst = W0T; KK = 1024; NN = 512; t0 = wid; }
    else if (wid < 192) { Wsrc = W1; Wdst = W1T; KK = 512;  NN = 512; t0 = wid - 128; }
    else                { Wsrc = W2; Wdst = W2T; KK = 512;  NN = 512; t0 = wid - 192; }
    int k0 = (t0 >> 3) << 6;        // NN/64 == 8 n-tiles always
    int n0 = (t0 & 7) << 6;
    int kk = tid >> 4, nn = (tid & 15) << 2;
#pragma unroll
    for (int s = 0; s < 4; ++s) {
      float4 v = *(const float4*)&Wsrc[(size_t)(k0 + s * 16 + kk) * NN + n0 + nn];
      tld[nn + 0][s * 16 + kk] = (bf16)v.x;
      tld[nn + 1][s * 16 + kk] = (bf16)v.y;
      tld[nn + 2][s * 16 + kk] = (bf16)v.z;
      tld[nn + 3][s * 16 + kk] = (bf16)v.w;
    }
    __syncthreads();
#pragma unroll
    for (int p2 = 0; p2 < 2; ++p2) {
      int seg = p2 * 256 + tid;
      int nn2 = seg >> 3, kk2 = (seg & 7) << 3;
      bf16x8 val;
#pragma unroll
      for (int j = 0; j < 8; ++j) val[j] = tld[nn2][kk2 + j];
      *(bf16x8*)&Wdst[(size_t)(n0 + nn2) * KK + k0 + kk2] = val;
    }
  }
}

// ================= 256x256 8-phase MFMA GEMM (m201 template port) =========
#define BAR  __builtin_amdgcn_s_barrier()
#define WAITL do { asm volatile("s_waitcnt lgkmcnt(0)" ::: "memory"); \
                   __builtin_amdgcn_sched_barrier(0); } while (0)
#define WAITV4 do { asm volatile("s_waitcnt vmcnt(4)" ::: "memory"); \
                    __builtin_amdgcn_sched_barrier(0); } while (0)

__global__ __launch_bounds__(512, 2) void gemm256(const bf16* __restrict__ A,
                                                  const bf16* __restrict__ BT,
                                                  bf16* __restrict__ C,
                                                  int K) {
  __shared__ __align__(16) bf16 SMEM[65536];   // 128 KiB
  bf16 (*As)[16384] = (bf16(*)[16384])SMEM;
  bf16 (*Bs)[16384] = (bf16(*)[16384])(SMEM + 32768);
  const int tid = threadIdx.x;
  const int lane = tid & 63;
  const int wave = tid >> 6;
  const int wr = wave >> 2;          // 0..1 (128 rows each)
  const int wc = wave & 3;           // 0..3 (64 cols each)
  const int T = K >> 6;              // K-tiles

  const int p = blockIdx.x;
  const int chunk = gridDim.x >> 3;
  const int wg = (p & 7) * chunk + (p >> 3);
  const int m0 = (wg >> 1) * 256;
  const int n0 = (wg & 1) * 256;

  const int srow = tid >> 3;                       // 0..63
  const int scol8 = (tid & 7) ^ (srow & 7);        // inverse-swizzled col grp

#define STAGEA(t, h)                                                          \
  do {                                                                        \
    int kt_ = ((t) < T) ? (t) * 64 : 0;                                       \
    const bf16* s_ = A + (size_t)(m0 + (h) * 128 + srow) * K + kt_ + scol8*8; \
    bf16* d_ = &As[(t) & 1][(h) * 8192 + wave * 512];                         \
    load_lds16(s_, d_);                                                       \
    load_lds16(s_ + (size_t)64 * K, d_ + 4096);                               \
  } while (0)
#define STAGEB(t, h)                                                          \
  do {                                                                        \
    int kt_ = ((t) < T) ? (t) * 64 : 0;                                       \
    const bf16* s_ = BT + (size_t)(n0 + (h) * 128 + srow) * K + kt_ + scol8*8;\
    bf16* d_ = &Bs[(t) & 1][(h) * 8192 + wave * 512];                         \
    load_lds16(s_, d_);                                                       \
    load_lds16(s_ + (size_t)64 * K, d_ + 4096);                               \
  } while (0)

  const int abase = (wr * 128 + (lane & 15)) * 64 + (lane >> 4) * 8;
  const int bbase = (wc * 64 + (lane & 15)) * 64 + (lane >> 4) * 8;
  const int axor = (lane & 7) << 3;

  bf16x8 areg[4][2], breg[4][2];
  f32x4 acc[8][4];
#pragma unroll
  for (int i = 0; i < 8; ++i)
#pragma unroll
    for (int j = 0; j < 4; ++j)
#pragma unroll
      for (int r = 0; r < 4; ++r) acc[i][j][r] = 0.0f;

#define LDA(buf_, qm)                                                         \
  _Pragma("unroll") for (int i_ = 0; i_ < 4; ++i_)                            \
  _Pragma("unroll") for (int h2_ = 0; h2_ < 2; ++h2_)                         \
    areg[i_][h2_] = *(const bf16x8*)&As[buf_][                                \
        (abase + ((qm)*4 + i_) * 1024 + h2_ * 32) ^ axor];
#define LDB(buf_, qn)                                                         \
  _Pragma("unroll") for (int j_ = 0; j_ < 2; ++j_)                            \
  _Pragma("unroll") for (int h2_ = 0; h2_ < 2; ++h2_)                         \
    breg[(qn)*2 + j_][h2_] = *(const bf16x8*)&Bs[buf_][                       \
        (bbase + ((qn)*2 + j_) * 1024 + h2_ * 32) ^ axor];
#define MFMAQ(qm, qn)                                                         \
  __builtin_amdgcn_s_setprio(1);                                              \
  _Pragma("unroll") for (int i_ = 0; i_ < 4; ++i_)                            \
  _Pragma("unroll") for (int j_ = 0; j_ < 2; ++j_)                            \
  _Pragma("unroll") for (int h2_ = 0; h2_ < 2; ++h2_)                         \
    acc[(qm)*4 + i_][(qn)*2 + j_] = __builtin_amdgcn_mfma_f32_16x16x32_bf16(  \
        areg[i_][h2_], breg[(qn)*2 + j_][h2_], acc[(qm)*4 + i_][(qn)*2 + j_], \
        0, 0, 0);                                                             \
  __builtin_amdgcn_s_setprio(0);

  STAGEA(0, 0); STAGEA(0, 1); STAGEB(0, 0); STAGEB(0, 1);
  STAGEB(1, 0); STAGEB(1, 1);
  WAITV4;
  BAR;

  const int NIT = T >> 1;
  for (int it = 0; it < NIT; ++it) {
    const int t1 = 2 * it + 1, t2 = 2 * it + 2, t3 = 2 * it + 3;
    LDA(0, 0); LDB(0, 0); STAGEA(t1, 0);
    BAR; WAITL; MFMAQ(0, 0); BAR;
    LDB(0, 1); STAGEA(t1, 1);
    BAR; WAITL; MFMAQ(0, 1); BAR;
    LDA(0, 1); STAGEB(t2, 0);
    BAR; WAITL; MFMAQ(1, 0); BAR;
    STAGEB(t2, 1);
    BAR; WAITL; MFMAQ(1, 1); WAITV4; BAR;
    LDA(1, 0); LDB(1, 0); STAGEA(t2, 0);
    BAR; WAITL; MFMAQ(0, 0); BAR;
    LDB(1, 1); STAGEA(t2, 1);
    BAR; WAITL; MFMAQ(0, 1); BAR;
    LDA(1, 1); STAGEB(t3, 0);
    BAR; WAITL; MFMAQ(1, 0); BAR;
    STAGEB(t3, 1);
    BAR; WAITL; MFMAQ(1, 1); WAITV4; BAR;
  }

  // ---- LDS-staged epilogue: acc -> SMEM (bf16, swizzled) -> coalesced out
  const int cn = lane & 15;
  const int rb = (lane >> 4) * 4;
#pragma unroll
  for (int i = 0; i < 8; ++i)
#pragma unroll
    for (int j = 0; j < 4; ++j) {
      int row = wr * 128 + i * 16 + rb;
      int colb = wc * 64 + j * 16 + cn;
#pragma unroll
      for (int r = 0; r < 4; ++r)
        SMEM[((row + r) << 8) + (colb ^ (((row + r) & 7) << 4))] =
            (bf16)acc[i][j][r];
    }
  __syncthreads();
  const size_t cbase = (size_t)m0 * MDIM + n0;
#pragma unroll
  for (int q = 0; q < 16; ++q) {
    int e = q * 4096 + tid * 8;
    int row = e >> 8, col = e & 255;
    *(bf16x8*)&C[cbase + (size_t)row * MDIM + col] =
        *(const bf16x8*)&SMEM[(row << 8) + (col ^ ((row & 7) << 4))];
  }
}

// ---------------- sparse aggregation + bias + degree-norm + relu ----------
// 8 rows per block; gather loop 4-unrolled for memory-level parallelism.
__global__ __launch_bounds__(128) void agg_kernel(const bf16* __restrict__ P,
                                                  const unsigned short* __restrict__ nbr,
                                                  const int* __restrict__ cnt,
                                                  const float* __restrict__ denomv,
                                                  const float* __restrict__ bias,
                                                  bf16* __restrict__ outb) {
  const int p = blockIdx.x;                      // 4096 blocks
  const int row0 = (p & 7) * 4096 + (p >> 3) * 8;  // XCD L2-affinity kept
  const int tid = threadIdx.x;                   // 128, 4 cols each
  const int b = row0 >> 9;
  __shared__ unsigned short nl[8][512];
  __shared__ int ncnt[8];
  if (tid < 8) ncnt[tid] = cnt[row0 + tid];
  __syncthreads();
#pragma unroll
  for (int r = 0; r < 8; ++r) {
    int n = ncnt[r];
    for (int i = tid; i < n; i += 128)
      nl[r][i] = nbr[(size_t)(row0 + r) * 512 + i];
  }
  __syncthreads();
  const bf16* Pb = P + ((size_t)(b << 9)) * MDIM;
  const int col = tid * 4;
  const float4 bb = *(const float4*)&bias[col];
#pragma unroll 2
  for (int r = 0; r < 8; ++r) {
    const int n = ncnt[r];
    float a0 = 0, a1 = 0, a2 = 0, a3 = 0;
    int e = 0;
    for (; e + 4 <= n; e += 4) {     // 4 independent gathers in flight
      bf16x4 v0 = *(const bf16x4*)&Pb[(size_t)nl[r][e + 0] * MDIM + col];
      bf16x4 v1 = *(const bf16x4*)&Pb[(size_t)nl[r][e + 1] * MDIM + col];
      bf16x4 v2 = *(const bf16x4*)&Pb[(size_t)nl[r][e + 2] * MDIM + col];
      bf16x4 v3 = *(const bf16x4*)&Pb[(size_t)nl[r][e + 3] * MDIM + col];
      a0 += (float)v0[0]; a1 += (float)v0[1]; a2 += (float)v0[2]; a3 += (float)v0[3];
      a0 += (float)v1[0]; a1 += (float)v1[1]; a2 += (float)v1[2]; a3 += (float)v1[3];
      a0 += (float)v2[0]; a1 += (float)v2[1]; a2 += (float)v2[2]; a3 += (float)v2[3];
      a0 += (float)v3[0]; a1 += (float)v3[1]; a2 += (float)v3[2]; a3 += (float)v3[3];
    }
    for (; e < n; ++e) {
      bf16x4 v = *(const bf16x4*)&Pb[(size_t)nl[r][e] * MDIM + col];
      a0 += (float)v[0]; a1 += (float)v[1]; a2 += (float)v[2]; a3 += (float)v[3];
    }
    float inv = 1.0f / denomv[row0 + r];
    bf16x4 o;
    o[0] = (bf16)fmaxf((a0 + bb.x) * inv, 0.0f);
    o[1] = (bf16)fmaxf((a1 + bb.y) * inv, 0.0f);
    o[2] = (bf16)fmaxf((a2 + bb.z) * inv, 0.0f);
    o[3] = (bf16)fmaxf((a3 + bb.w) * inv, 0.0f);
    *(bf16x4*)&outb[(size_t)(row0 + r) * MDIM + col] = o;
  }
}

// ---------------- layer-3 aggregation fused with pooling partials ---------
__global__ __launch_bounds__(128) void agg_pool_kernel(
    const bf16* __restrict__ P, const unsigned short* __restrict__ nbr,
    const int* __restrict__ cnt, const float* __restrict__ denomv,
    const float* __restrict__ bias, const int* __restrict__ amask,
    float* __restrict__ part) {
  const int p = blockIdx.x;                      // 4096 blocks
  const int row0 = (p & 7) * 4096 + (p >> 3) * 8;
  const int tid = threadIdx.x;                   // 128, 4 cols each
  const int b = row0 >> 9;
  __shared__ unsigned short nl[8][512];
  __shared__ int ncnt[8];
  if (tid < 8) ncnt[tid] = cnt[row0 + tid];
  __syncthreads();
#pragma unroll
  for (int r = 0; r < 8; ++r) {
    int n = ncnt[r];
    for (int i = tid; i < n; i += 128)
      nl[r][i] = nbr[(size_t)(row0 + r) * 512 + i];
  }
  __syncthreads();
  const bf16* Pb = P + ((size_t)(b << 9)) * MDIM;
  const int col = tid * 4;
  const float4 bb = *(const float4*)&bias[col];
  float m0 = 0, m1 = 0, m2 = 0, m3 = 0;   // masked (dep) sums
  float g0 = 0, g1 = 0, g2 = 0, g3 = 0;   // plain (glob) sums
#pragma unroll 2
  for (int r = 0; r < 8; ++r) {
    const int n = ncnt[r];
    float a0 = 0, a1 = 0, a2 = 0, a3 = 0;
    int e = 0;
    for (; e + 4 <= n; e += 4) {
      bf16x4 v0 = *(const bf16x4*)&Pb[(size_t)nl[r][e + 0] * MDIM + col];
      bf16x4 v1 = *(const bf16x4*)&Pb[(size_t)nl[r][e + 1] * MDIM + col];
      bf16x4 v2 = *(const bf16x4*)&Pb[(size_t)nl[r][e + 2] * MDIM + col];
      bf16x4 v3 = *(const bf16x4*)&Pb[(size_t)nl[r][e + 3] * MDIM + col];
      a0 += (float)v0[0]; a1 += (float)v0[1]; a2 += (float)v0[2]; a3 += (float)v0[3];
      a0 += (float)v1[0]; a1 += (float)v1[1]; a2 += (float)v1[2]; a3 += (float)v1[3];
      a0 += (float)v2[0]; a1 += (float)v2[1]; a2 += (float)v2[2]; a3 += (float)v2[3];
      a0 += (float)v3[0]; a1 += (float)v3[1]; a2 += (float)v3[2]; a3 += (float)v3[3];
    }
    for (; e < n; ++e) {
      bf16x4 v = *(const bf16x4*)&Pb[(size_t)nl[r][e] * MDIM + col];
      a0 += (float)v[0]; a1 += (float)v[1]; a2 += (float)v[2]; a3 += (float)v[3];
    }
    float inv = 1.0f / denomv[row0 + r];
    float o0 = fmaxf((a0 + bb.x) * inv, 0.0f);
    float o1 = fmaxf((a1 + bb.y) * inv, 0.0f);
    float o2 = fmaxf((a2 + bb.z) * inv, 0.0f);
    float o3 = fmaxf((a3 + bb.w) * inv, 0.0f);
    float tg = (float)amask[row0 + r];
    g0 += o0; g1 += o1; g2 += o2; g3 += o3;
    m0 += o0 * tg; m1 += o1 * tg; m2 += o2 * tg; m3 += o3 * tg;
  }
  float* pp = part + (size_t)p * 1024;
  pp[col + 0] = m0; pp[col + 1] = m1; pp[col + 2] = m2; pp[col + 3] = m3;
  pp[512 + col + 0] = g0; pp[512 + col + 1] = g1;
  pp[512 + col + 2] = g2; pp[512 + col + 3] = g3;
}

// ---------------- pool finish + classifier + softmax (+ loss, block 64) ---
// Batch b's rows live in the 64 agg_pool blocks p = ((b&7)*64+j)<<3 | (b>>3).
__global__ __launch_bounds__(512) void poolcls_kernel(
    const float* __restrict__ part, const int* __restrict__ amask,
    const float* __restrict__ loss_arr, const float* __restrict__ cw,
    const float* __restrict__ cb, float* __restrict__ outp) {
  __shared__ float tg[512];
  __shared__ float shr[3][8];
  const int tid = threadIdx.x;
  const int b = blockIdx.x;

  if (b == 64) {
    float s = 0.0f;
    for (int i = tid; i < NROWS; i += 512) s += loss_arr[i];
    s = wave_reduce_sum(s);
    if ((tid & 63) == 0) shr[0][tid >> 6] = s;
    __syncthreads();
    if (tid == 0) {
      float t = 0.0f;
#pragma unroll
      for (int k = 0; k < 8; ++k) t += shr[0][k];
      outp[33152] = t * (1.0f / 32768.0f);
    }
    return;
  }

  tg[tid] = (float)amask[b * 512 + tid];
  __syncthreads();
  float wn = 0.0f;
#pragma unroll 8
  for (int s = 0; s < 512; ++s) wn += tg[s];

  const int x = b >> 3;                // XCD of this batch's rows
  const int qbase = (b & 7) * 64;
  float t = 0.0f, a = 0.0f;
#pragma unroll 4
  for (int j = 0; j < 64; ++j) {
    const float* pp = part + (size_t)(((qbase + j) << 3) | x) * 1024;
    t += pp[tid];
    a += pp[512 + tid];
  }
  float f1 = t / wn;                 // dep feature (col tid)
  float f2 = a * (1.0f / 512.0f);    // glob feature (col tid)

  float p0 = f1 * cw[tid * 3 + 0] + f2 * cw[(512 + tid) * 3 + 0];
  float p1 = f1 * cw[tid * 3 + 1] + f2 * cw[(512 + tid) * 3 + 1];
  float p2 = f1 * cw[tid * 3 + 2] + f2 * cw[(512 + tid) * 3 + 2];
  p0 = wave_reduce_sum(p0);
  p1 = wave_reduce_sum(p1);
  p2 = wave_reduce_sum(p2);
  if ((tid & 63) == 0) {
    shr[0][tid >> 6] = p0; shr[1][tid >> 6] = p1; shr[2][tid >> 6] = p2;
  }
  __syncthreads();
  if (tid == 0) {
    float q0 = 0, q1 = 0, q2 = 0;
#pragma unroll
    for (int k = 0; k < 8; ++k) { q0 += shr[0][k]; q1 += shr[1][k]; q2 += shr[2][k]; }
    q0 += cb[0]; q1 += cb[1]; q2 += cb[2];
    outp[b * 3 + 0] = q0;
    outp[b * 3 + 1] = q1;
    outp[b * 3 + 2] = q2;
    float m = fmaxf(q0, fmaxf(q1, q2));
    float e0 = expf(q0 - m), e1 = expf(q1 - m), e2 = expf(q2 - m);
    float inv = 1.0f / (e0 + e1 + e2);
    outp[192 + b * 3 + 0] = e0 * inv;
    outp[192 + b * 3 + 1] = e1 * inv;
    outp[192 + b * 3 + 2] = e2 * inv;
  }
}

extern "C" void kernel_launch(void* const* d_in, const int* in_sizes, int n_in,
                              void* d_out, int out_size, void* d_ws, size_t ws_size,
                              hipStream_t stream) {
  const float* seq   = (const float*)d_in[0];
  const float* adj   = (const float*)d_in[1];
  const int*   amask = (const int*)d_in[2];
  const float* ln_a  = (const float*)d_in[3];
  const float* ln_b  = (const float*)d_in[4];
  const float* asp_w = (const float*)d_in[5];
  const float* asp_b = (const float*)d_in[6];
  const float* W0    = (const float*)d_in[7];
  const float* b0    = (const float*)d_in[8];
  const float* W1    = (const float*)d_in[9];
  const float* b1    = (const float*)d_in[10];
  const float* W2    = (const float*)d_in[11];
  const float* b2    = (const float*)d_in[12];
  const float* cls_w = (const float*)d_in[13];
  const float* cls_b = (const float*)d_in[14];
  float* out = (float*)d_out;

  char* w = (char*)d_ws;
  bf16* P             = (bf16*)w;           w += (size_t)NROWS * MDIM * 2;  // 32 MB
  bf16* xn            = (bf16*)w;           w += (size_t)NROWS * DDIM * 2;  // 64 MB
  bf16* outb          = (bf16*)w;           w += (size_t)NROWS * MDIM * 2;  // 32 MB
  unsigned short* nbr = (unsigned short*)w; w += (size_t)NROWS * 512 * 2;   // 32 MB
  int* cnt            = (int*)w;            w += (size_t)NROWS * 4;
  float* denomv       = (float*)w;          w += (size_t)NROWS * 4;
  float* loss_arr     = (float*)w;          w += (size_t)NROWS * 4;
  float* part         = (float*)w;          w += (size_t)4096 * 1024 * 4;   // 16 MB
  bf16* W0T           = (bf16*)w;           w += (size_t)512 * 1024 * 2;
  bf16* W1T           = (bf16*)w;           w += (size_t)512 * 512 * 2;
  bf16* W2T           = (bf16*)w;           w += (size_t)512 * 512 * 2;

  // 1. LayerNorm + aspect head: async-LDS pipelined (global_load_lds MLP)
  ln_kernel<<<1024, 256, 0, stream>>>(seq, amask, ln_a, ln_b, asp_w, asp_b,
                                      xn, out + 384, loss_arr);
  // 2. neighbor-list build | weight cast+transpose
  nbrw_kernel<<<8448, 256, 0, stream>>>(adj, W0, W1, W2, nbr, cnt, denomv,
                                        W0T, W1T, W2T);
  // 3-7. GCN layers: P = in @ W (MFMA), then sparse agg + bias/denom/relu.
  // Layer 3's agg is fused with the pooling partial sums (no outb write).
  gemm256<<<256, 512, 0, stream>>>(xn, W0T, P, 1024);
  agg_kernel<<<4096, 128, 0, stream>>>(P, nbr, cnt, denomv, b0, outb);
  gemm256<<<256, 512, 0, stream>>>(outb, W1T, P, 512);
  agg_kernel<<<4096, 128, 0, stream>>>(P, nbr, cnt, denomv, b1, outb);
  gemm256<<<256, 512, 0, stream>>>(outb, W2T, P, 512);
  agg_pool_kernel<<<4096, 128, 0, stream>>>(P, nbr, cnt, denomv, b2, amask,
                                            part);
  // 8. pool finish + classifier + softmax (+ loss)
  poolcls_kernel<<<65, 512, 0, stream>>>(part, amask, loss_arr, cls_w, cls_b,
                                         out);
}

// Round 14
// 241.678 us; speedup vs baseline: 1.0516x; 1.0516x over previous
//
#include <hip/hip_runtime.h>
#include <math.h>

typedef __bf16 bf16;
typedef bf16 bf16x2 __attribute__((ext_vector_type(2)));
typedef bf16 bf16x4 __attribute__((ext_vector_type(4)));
typedef bf16 bf16x8 __attribute__((ext_vector_type(8)));
typedef float f32x4 __attribute__((ext_vector_type(4)));

// Problem constants: B=64, S=512, D=1024, M=512, P=3
#define NROWS 32768   // B*S
#define DDIM 1024
#define MDIM 512

__device__ __forceinline__ float wave_reduce_sum(float v) {   // lane0 gets total
#pragma unroll
  for (int o = 32; o > 0; o >>= 1) v += __shfl_down(v, o, 64);
  return v;
}
__device__ __forceinline__ float wave_allreduce_sum(float v) { // all lanes get total
#pragma unroll
  for (int o = 32; o > 0; o >>= 1) v += __shfl_xor(v, o, 64);
  return v;
}

// async global->LDS, 16B per lane. LDS dest is wave-uniform base + lane*16.
__device__ __forceinline__ void load_lds16(const bf16* g, bf16* l) {
  __builtin_amdgcn_global_load_lds(
      (const __attribute__((address_space(1))) unsigned int*)g,
      (__attribute__((address_space(3))) unsigned int*)l, 16, 0, 0);
}

// ================= fused prep: ln_head | build_nbr | wcast ================
// wave-per-row (proven structure). Streaming data (seq, adj reads; xn
// writes) uses nontemporal hints: zero reuse -> keep it out of L2 so the
// read stream and write-allocate stream stop thrashing each other.
// grid: [0,8192) ln; [8192,16384) nbr; [16384,16640) wcast.
// NOTE (R13 post-mortem): the three sections MUST stay in one dispatch —
// their co-residency is what hides ln's cold-miss latency (splitting cost
// +12 µs). Four ILP/MLP attacks on ln all failed; this is the floor.
__global__ __launch_bounds__(256) void prep_kernel(
    const float* __restrict__ seq, const float* __restrict__ adj,
    const int* __restrict__ amask, const float* __restrict__ ga,
    const float* __restrict__ gb, const float* __restrict__ aw,
    const float* __restrict__ ab, const float* __restrict__ W0,
    const float* __restrict__ W1, const float* __restrict__ W2,
    bf16* __restrict__ xn, float* __restrict__ aspect_pred,
    float* __restrict__ loss_arr, unsigned short* __restrict__ nbr,
    int* __restrict__ cnt, float* __restrict__ denomv,
    bf16* __restrict__ W0T, bf16* __restrict__ W1T, bf16* __restrict__ W2T) {
  const int bid = blockIdx.x;
  const int tid = threadIdx.x;
  const int lane = tid & 63;
  const int wv = tid >> 6;

  if (bid < 8192) {
    // ---------------- LayerNorm + aspect head (one wave per row) ----------
    const int row = bid * 4 + wv;
    const float* xr = seq + (size_t)row * DDIM;
    f32x4 v[4];
    float s = 0.0f, sq = 0.0f;
#pragma unroll
    for (int j = 0; j < 4; ++j) {
      v[j] = __builtin_nontemporal_load((const f32x4*)&xr[j * 256 + lane * 4]);
      s += v[j].x + v[j].y + v[j].z + v[j].w;
      sq += v[j].x * v[j].x + v[j].y * v[j].y + v[j].z * v[j].z + v[j].w * v[j].w;
    }
    s = wave_allreduce_sum(s);
    sq = wave_allreduce_sum(sq);
    float mean = s * (1.0f / 1024.0f);
    float var = (sq - 1024.0f * mean * mean) * (1.0f / 1023.0f);  // unbiased
    var = fmaxf(var, 0.0f);
    float inv = 1.0f / (sqrtf(var) + 1e-6f);
    float zp = 0.0f;
#pragma unroll
    for (int j = 0; j < 4; ++j) {
      int c = j * 256 + lane * 4;
      float4 a4 = *(const float4*)&ga[c];     // reused across blocks: cached
      float4 b4 = *(const float4*)&gb[c];
      float4 w4 = *(const float4*)&aw[c];
      float x0 = a4.x * (v[j].x - mean) * inv + b4.x;
      float x1 = a4.y * (v[j].y - mean) * inv + b4.y;
      float x2 = a4.z * (v[j].z - mean) * inv + b4.z;
      float x3 = a4.w * (v[j].w - mean) * inv + b4.w;
      bf16x4 o;
      o[0] = (bf16)x0; o[1] = (bf16)x1; o[2] = (bf16)x2; o[3] = (bf16)x3;
      __builtin_nontemporal_store(o, (bf16x4*)&xn[(size_t)row * DDIM + c]);
      zp += x0 * w4.x + x1 * w4.y + x2 * w4.z + x3 * w4.w;
    }
    zp = wave_reduce_sum(zp);
    if (lane == 0) {
      float z = zp + ab[0];
      aspect_pred[row] = 1.0f / (1.0f + expf(-z));
      float tgt = (float)amask[row];
      float bce = fmaxf(z, 0.0f) + log1pf(expf(-fabsf(z))) - z * tgt;
      loss_arr[row] = tgt * bce;
    }
  } else if (bid < 16384) {
    // ---------------- neighbor-list build (one wave per row) --------------
    const int row = (bid - 8192) * 4 + wv;
    const float* ar = adj + (size_t)row * 512;
    unsigned short* nr = nbr + (size_t)row * 512;
    unsigned long long below = (1ull << lane) - 1ull;
    int base = 0;
#pragma unroll
    for (int t = 0; t < 2; ++t) {
      f32x4 v = __builtin_nontemporal_load((const f32x4*)&ar[t * 256 + lane * 4]);
      unsigned long long m0 = __ballot(v.x != 0.0f);
      unsigned long long m1 = __ballot(v.y != 0.0f);
      unsigned long long m2 = __ballot(v.z != 0.0f);
      unsigned long long m3 = __ballot(v.w != 0.0f);
      int c0 = __popcll(m0), c1 = __popcll(m1), c2 = __popcll(m2);
      int col = t * 256 + lane * 4;
      if (v.x != 0.0f) nr[base + __popcll(m0 & below)] = (unsigned short)(col + 0);
      if (v.y != 0.0f) nr[base + c0 + __popcll(m1 & below)] = (unsigned short)(col + 1);
      if (v.z != 0.0f) nr[base + c0 + c1 + __popcll(m2 & below)] = (unsigned short)(col + 2);
      if (v.w != 0.0f) nr[base + c0 + c1 + c2 + __popcll(m3 & below)] = (unsigned short)(col + 3);
      base += c0 + c1 + c2 + __popcll(m3);
    }
    if (lane == 0) { cnt[row] = base; denomv[row] = (float)base + 1.0f; }
  } else {
    // -------- weight cast+transpose via LDS 64x64 tiles -------------------
    __shared__ bf16 tld[64][72];   // +8 pad
    int wid = bid - 16384;
    const float* Wsrc; bf16* Wdst; int KK, NN, t0;
    if (wid < 128)      { Wsrc = W0; Wdst = W0T; KK = 1024; NN = 512; t0 = wid; }
    else if (wid < 192) { Wsrc = W1; Wdst = W1T; KK = 512;  NN = 512; t0 = wid - 128; }
    else                { Wsrc = W2; Wdst = W2T; KK = 512;  NN = 512; t0 = wid - 192; }
    int k0 = (t0 >> 3) << 6;        // NN/64 == 8 n-tiles always
    int n0 = (t0 & 7) << 6;
    int kk = tid >> 4, nn = (tid & 15) << 2;
#pragma unroll
    for (int s = 0; s < 4; ++s) {
      float4 v = *(const float4*)&Wsrc[(size_t)(k0 + s * 16 + kk) * NN + n0 + nn];
      tld[nn + 0][s * 16 + kk] = (bf16)v.x;
      tld[nn + 1][s * 16 + kk] = (bf16)v.y;
      tld[nn + 2][s * 16 + kk] = (bf16)v.z;
      tld[nn + 3][s * 16 + kk] = (bf16)v.w;
    }
    __syncthreads();
#pragma unroll
    for (int p2 = 0; p2 < 2; ++p2) {
      int seg = p2 * 256 + tid;
      int nn2 = seg >> 3, kk2 = (seg & 7) << 3;
      bf16x8 val;
#pragma unroll
      for (int j = 0; j < 8; ++j) val[j] = tld[nn2][kk2 + j];
      *(bf16x8*)&Wdst[(size_t)(n0 + nn2) * KK + k0 + kk2] = val;
    }
  }
}

// ================= 256x256 8-phase MFMA GEMM (m201 template port) =========
#define BAR  __builtin_amdgcn_s_barrier()
#define WAITL do { asm volatile("s_waitcnt lgkmcnt(0)" ::: "memory"); \
                   __builtin_amdgcn_sched_barrier(0); } while (0)
#define WAITV4 do { asm volatile("s_waitcnt vmcnt(4)" ::: "memory"); \
                    __builtin_amdgcn_sched_barrier(0); } while (0)

__global__ __launch_bounds__(512, 2) void gemm256(const bf16* __restrict__ A,
                                                  const bf16* __restrict__ BT,
                                                  bf16* __restrict__ C,
                                                  int K) {
  __shared__ __align__(16) bf16 SMEM[65536];   // 128 KiB
  bf16 (*As)[16384] = (bf16(*)[16384])SMEM;
  bf16 (*Bs)[16384] = (bf16(*)[16384])(SMEM + 32768);
  const int tid = threadIdx.x;
  const int lane = tid & 63;
  const int wave = tid >> 6;
  const int wr = wave >> 2;          // 0..1 (128 rows each)
  const int wc = wave & 3;           // 0..3 (64 cols each)
  const int T = K >> 6;              // K-tiles

  const int p = blockIdx.x;
  const int chunk = gridDim.x >> 3;
  const int wg = (p & 7) * chunk + (p >> 3);
  const int m0 = (wg >> 1) * 256;
  const int n0 = (wg & 1) * 256;

  const int srow = tid >> 3;                       // 0..63
  const int scol8 = (tid & 7) ^ (srow & 7);        // inverse-swizzled col grp

#define STAGEA(t, h)                                                          \
  do {                                                                        \
    int kt_ = ((t) < T) ? (t) * 64 : 0;                                       \
    const bf16* s_ = A + (size_t)(m0 + (h) * 128 + srow) * K + kt_ + scol8*8; \
    bf16* d_ = &As[(t) & 1][(h) * 8192 + wave * 512];                         \
    load_lds16(s_, d_);                                                       \
    load_lds16(s_ + (size_t)64 * K, d_ + 4096);                               \
  } while (0)
#define STAGEB(t, h)                                                          \
  do {                                                                        \
    int kt_ = ((t) < T) ? (t) * 64 : 0;                                       \
    const bf16* s_ = BT + (size_t)(n0 + (h) * 128 + srow) * K + kt_ + scol8*8;\
    bf16* d_ = &Bs[(t) & 1][(h) * 8192 + wave * 512];                         \
    load_lds16(s_, d_);                                                       \
    load_lds16(s_ + (size_t)64 * K, d_ + 4096);                               \
  } while (0)

  const int abase = (wr * 128 + (lane & 15)) * 64 + (lane >> 4) * 8;
  const int bbase = (wc * 64 + (lane & 15)) * 64 + (lane >> 4) * 8;
  const int axor = (lane & 7) << 3;

  bf16x8 areg[4][2], breg[4][2];
  f32x4 acc[8][4];
#pragma unroll
  for (int i = 0; i < 8; ++i)
#pragma unroll
    for (int j = 0; j < 4; ++j)
#pragma unroll
      for (int r = 0; r < 4; ++r) acc[i][j][r] = 0.0f;

#define LDA(buf_, qm)                                                         \
  _Pragma("unroll") for (int i_ = 0; i_ < 4; ++i_)                            \
  _Pragma("unroll") for (int h2_ = 0; h2_ < 2; ++h2_)                         \
    areg[i_][h2_] = *(const bf16x8*)&As[buf_][                                \
        (abase + ((qm)*4 + i_) * 1024 + h2_ * 32) ^ axor];
#define LDB(buf_, qn)                                                         \
  _Pragma("unroll") for (int j_ = 0; j_ < 2; ++j_)                            \
  _Pragma("unroll") for (int h2_ = 0; h2_ < 2; ++h2_)                         \
    breg[(qn)*2 + j_][h2_] = *(const bf16x8*)&Bs[buf_][                       \
        (bbase + ((qn)*2 + j_) * 1024 + h2_ * 32) ^ axor];
#define MFMAQ(qm, qn)                                                         \
  __builtin_amdgcn_s_setprio(1);                                              \
  _Pragma("unroll") for (int i_ = 0; i_ < 4; ++i_)                            \
  _Pragma("unroll") for (int j_ = 0; j_ < 2; ++j_)                            \
  _Pragma("unroll") for (int h2_ = 0; h2_ < 2; ++h2_)                         \
    acc[(qm)*4 + i_][(qn)*2 + j_] = __builtin_amdgcn_mfma_f32_16x16x32_bf16(  \
        areg[i_][h2_], breg[(qn)*2 + j_][h2_], acc[(qm)*4 + i_][(qn)*2 + j_], \
        0, 0, 0);                                                             \
  __builtin_amdgcn_s_setprio(0);

  STAGEA(0, 0); STAGEA(0, 1); STAGEB(0, 0); STAGEB(0, 1);
  STAGEB(1, 0); STAGEB(1, 1);
  WAITV4;
  BAR;

  const int NIT = T >> 1;
  for (int it = 0; it < NIT; ++it) {
    const int t1 = 2 * it + 1, t2 = 2 * it + 2, t3 = 2 * it + 3;
    LDA(0, 0); LDB(0, 0); STAGEA(t1, 0);
    BAR; WAITL; MFMAQ(0, 0); BAR;
    LDB(0, 1); STAGEA(t1, 1);
    BAR; WAITL; MFMAQ(0, 1); BAR;
    LDA(0, 1); STAGEB(t2, 0);
    BAR; WAITL; MFMAQ(1, 0); BAR;
    STAGEB(t2, 1);
    BAR; WAITL; MFMAQ(1, 1); WAITV4; BAR;
    LDA(1, 0); LDB(1, 0); STAGEA(t2, 0);
    BAR; WAITL; MFMAQ(0, 0); BAR;
    LDB(1, 1); STAGEA(t2, 1);
    BAR; WAITL; MFMAQ(0, 1); BAR;
    LDA(1, 1); STAGEB(t3, 0);
    BAR; WAITL; MFMAQ(1, 0); BAR;
    STAGEB(t3, 1);
    BAR; WAITL; MFMAQ(1, 1); WAITV4; BAR;
  }

  // ---- LDS-staged epilogue: acc -> SMEM (bf16, swizzled) -> coalesced out
  const int cn = lane & 15;
  const int rb = (lane >> 4) * 4;
#pragma unroll
  for (int i = 0; i < 8; ++i)
#pragma unroll
    for (int j = 0; j < 4; ++j) {
      int row = wr * 128 + i * 16 + rb;
      int colb = wc * 64 + j * 16 + cn;
#pragma unroll
      for (int r = 0; r < 4; ++r)
        SMEM[((row + r) << 8) + (colb ^ (((row + r) & 7) << 4))] =
            (bf16)acc[i][j][r];
    }
  __syncthreads();
  const size_t cbase = (size_t)m0 * MDIM + n0;
#pragma unroll
  for (int q = 0; q < 16; ++q) {
    int e = q * 4096 + tid * 8;
    int row = e >> 8, col = e & 255;
    *(bf16x8*)&C[cbase + (size_t)row * MDIM + col] =
        *(const bf16x8*)&SMEM[(row << 8) + (col ^ ((row & 7) << 4))];
  }
}

// ---------------- sparse aggregation + bias + degree-norm + relu ----------
// 8 rows per block; gather loop 4-unrolled for memory-level parallelism.
__global__ __launch_bounds__(128) void agg_kernel(const bf16* __restrict__ P,
                                                  const unsigned short* __restrict__ nbr,
                                                  const int* __restrict__ cnt,
                                                  const float* __restrict__ denomv,
                                                  const float* __restrict__ bias,
                                                  bf16* __restrict__ outb) {
  const int p = blockIdx.x;                      // 4096 blocks
  const int row0 = (p & 7) * 4096 + (p >> 3) * 8;  // XCD L2-affinity kept
  const int tid = threadIdx.x;                   // 128, 4 cols each
  const int b = row0 >> 9;
  __shared__ unsigned short nl[8][512];
  __shared__ int ncnt[8];
  if (tid < 8) ncnt[tid] = cnt[row0 + tid];
  __syncthreads();
#pragma unroll
  for (int r = 0; r < 8; ++r) {
    int n = ncnt[r];
    for (int i = tid; i < n; i += 128)
      nl[r][i] = nbr[(size_t)(row0 + r) * 512 + i];
  }
  __syncthreads();
  const bf16* Pb = P + ((size_t)(b << 9)) * MDIM;
  const int col = tid * 4;
  const float4 bb = *(const float4*)&bias[col];
#pragma unroll 2
  for (int r = 0; r < 8; ++r) {
    const int n = ncnt[r];
    float a0 = 0, a1 = 0, a2 = 0, a3 = 0;
    int e = 0;
    for (; e + 4 <= n; e += 4) {     // 4 independent gathers in flight
      bf16x4 v0 = *(const bf16x4*)&Pb[(size_t)nl[r][e + 0] * MDIM + col];
      bf16x4 v1 = *(const bf16x4*)&Pb[(size_t)nl[r][e + 1] * MDIM + col];
      bf16x4 v2 = *(const bf16x4*)&Pb[(size_t)nl[r][e + 2] * MDIM + col];
      bf16x4 v3 = *(const bf16x4*)&Pb[(size_t)nl[r][e + 3] * MDIM + col];
      a0 += (float)v0[0]; a1 += (float)v0[1]; a2 += (float)v0[2]; a3 += (float)v0[3];
      a0 += (float)v1[0]; a1 += (float)v1[1]; a2 += (float)v1[2]; a3 += (float)v1[3];
      a0 += (float)v2[0]; a1 += (float)v2[1]; a2 += (float)v2[2]; a3 += (float)v2[3];
      a0 += (float)v3[0]; a1 += (float)v3[1]; a2 += (float)v3[2]; a3 += (float)v3[3];
    }
    for (; e < n; ++e) {
      bf16x4 v = *(const bf16x4*)&Pb[(size_t)nl[r][e] * MDIM + col];
      a0 += (float)v[0]; a1 += (float)v[1]; a2 += (float)v[2]; a3 += (float)v[3];
    }
    float inv = 1.0f / denomv[row0 + r];
    bf16x4 o;
    o[0] = (bf16)fmaxf((a0 + bb.x) * inv, 0.0f);
    o[1] = (bf16)fmaxf((a1 + bb.y) * inv, 0.0f);
    o[2] = (bf16)fmaxf((a2 + bb.z) * inv, 0.0f);
    o[3] = (bf16)fmaxf((a3 + bb.w) * inv, 0.0f);
    *(bf16x4*)&outb[(size_t)(row0 + r) * MDIM + col] = o;
  }
}

// ---------------- layer-3 aggregation fused with pooling partials ---------
__global__ __launch_bounds__(128) void agg_pool_kernel(
    const bf16* __restrict__ P, const unsigned short* __restrict__ nbr,
    const int* __restrict__ cnt, const float* __restrict__ denomv,
    const float* __restrict__ bias, const int* __restrict__ amask,
    float* __restrict__ part) {
  const int p = blockIdx.x;                      // 4096 blocks
  const int row0 = (p & 7) * 4096 + (p >> 3) * 8;
  const int tid = threadIdx.x;                   // 128, 4 cols each
  const int b = row0 >> 9;
  __shared__ unsigned short nl[8][512];
  __shared__ int ncnt[8];
  if (tid < 8) ncnt[tid] = cnt[row0 + tid];
  __syncthreads();
#pragma unroll
  for (int r = 0; r < 8; ++r) {
    int n = ncnt[r];
    for (int i = tid; i < n; i += 128)
      nl[r][i] = nbr[(size_t)(row0 + r) * 512 + i];
  }
  __syncthreads();
  const bf16* Pb = P + ((size_t)(b << 9)) * MDIM;
  const int col = tid * 4;
  const float4 bb = *(const float4*)&bias[col];
  float m0 = 0, m1 = 0, m2 = 0, m3 = 0;   // masked (dep) sums
  float g0 = 0, g1 = 0, g2 = 0, g3 = 0;   // plain (glob) sums
#pragma unroll 2
  for (int r = 0; r < 8; ++r) {
    const int n = ncnt[r];
    float a0 = 0, a1 = 0, a2 = 0, a3 = 0;
    int e = 0;
    for (; e + 4 <= n; e += 4) {
      bf16x4 v0 = *(const bf16x4*)&Pb[(size_t)nl[r][e + 0] * MDIM + col];
      bf16x4 v1 = *(const bf16x4*)&Pb[(size_t)nl[r][e + 1] * MDIM + col];
      bf16x4 v2 = *(const bf16x4*)&Pb[(size_t)nl[r][e + 2] * MDIM + col];
      bf16x4 v3 = *(const bf16x4*)&Pb[(size_t)nl[r][e + 3] * MDIM + col];
      a0 += (float)v0[0]; a1 += (float)v0[1]; a2 += (float)v0[2]; a3 += (float)v0[3];
      a0 += (float)v1[0]; a1 += (float)v1[1]; a2 += (float)v1[2]; a3 += (float)v1[3];
      a0 += (float)v2[0]; a1 += (float)v2[1]; a2 += (float)v2[2]; a3 += (float)v2[3];
      a0 += (float)v3[0]; a1 += (float)v3[1]; a2 += (float)v3[2]; a3 += (float)v3[3];
    }
    for (; e < n; ++e) {
      bf16x4 v = *(const bf16x4*)&Pb[(size_t)nl[r][e] * MDIM + col];
      a0 += (float)v[0]; a1 += (float)v[1]; a2 += (float)v[2]; a3 += (float)v[3];
    }
    float inv = 1.0f / denomv[row0 + r];
    float o0 = fmaxf((a0 + bb.x) * inv, 0.0f);
    float o1 = fmaxf((a1 + bb.y) * inv, 0.0f);
    float o2 = fmaxf((a2 + bb.z) * inv, 0.0f);
    float o3 = fmaxf((a3 + bb.w) * inv, 0.0f);
    float tg = (float)amask[row0 + r];
    g0 += o0; g1 += o1; g2 += o2; g3 += o3;
    m0 += o0 * tg; m1 += o1 * tg; m2 += o2 * tg; m3 += o3 * tg;
  }
  float* pp = part + (size_t)p * 1024;
  pp[col + 0] = m0; pp[col + 1] = m1; pp[col + 2] = m2; pp[col + 3] = m3;
  pp[512 + col + 0] = g0; pp[512 + col + 1] = g1;
  pp[512 + col + 2] = g2; pp[512 + col + 3] = g3;
}

// ---------------- pool finish + classifier + softmax (+ loss, block 64) ---
// Batch b's rows live in the 64 agg_pool blocks p = ((b&7)*64+j)<<3 | (b>>3).
__global__ __launch_bounds__(512) void poolcls_kernel(
    const float* __restrict__ part, const int* __restrict__ amask,
    const float* __restrict__ loss_arr, const float* __restrict__ cw,
    const float* __restrict__ cb, float* __restrict__ outp) {
  __shared__ float tg[512];
  __shared__ float shr[3][8];
  const int tid = threadIdx.x;
  const int b = blockIdx.x;

  if (b == 64) {
    float s = 0.0f;
    for (int i = tid; i < NROWS; i += 512) s += loss_arr[i];
    s = wave_reduce_sum(s);
    if ((tid & 63) == 0) shr[0][tid >> 6] = s;
    __syncthreads();
    if (tid == 0) {
      float t = 0.0f;
#pragma unroll
      for (int k = 0; k < 8; ++k) t += shr[0][k];
      outp[33152] = t * (1.0f / 32768.0f);
    }
    return;
  }

  tg[tid] = (float)amask[b * 512 + tid];
  __syncthreads();
  float wn = 0.0f;
#pragma unroll 8
  for (int s = 0; s < 512; ++s) wn += tg[s];

  const int x = b >> 3;                // XCD of this batch's rows
  const int qbase = (b & 7) * 64;
  float t = 0.0f, a = 0.0f;
#pragma unroll 4
  for (int j = 0; j < 64; ++j) {
    const float* pp = part + (size_t)(((qbase + j) << 3) | x) * 1024;
    t += pp[tid];
    a += pp[512 + tid];
  }
  float f1 = t / wn;                 // dep feature (col tid)
  float f2 = a * (1.0f / 512.0f);    // glob feature (col tid)

  float p0 = f1 * cw[tid * 3 + 0] + f2 * cw[(512 + tid) * 3 + 0];
  float p1 = f1 * cw[tid * 3 + 1] + f2 * cw[(512 + tid) * 3 + 1];
  float p2 = f1 * cw[tid * 3 + 2] + f2 * cw[(512 + tid) * 3 + 2];
  p0 = wave_reduce_sum(p0);
  p1 = wave_reduce_sum(p1);
  p2 = wave_reduce_sum(p2);
  if ((tid & 63) == 0) {
    shr[0][tid >> 6] = p0; shr[1][tid >> 6] = p1; shr[2][tid >> 6] = p2;
  }
  __syncthreads();
  if (tid == 0) {
    float q0 = 0, q1 = 0, q2 = 0;
#pragma unroll
    for (int k = 0; k < 8; ++k) { q0 += shr[0][k]; q1 += shr[1][k]; q2 += shr[2][k]; }
    q0 += cb[0]; q1 += cb[1]; q2 += cb[2];
    outp[b * 3 + 0] = q0;
    outp[b * 3 + 1] = q1;
    outp[b * 3 + 2] = q2;
    float m = fmaxf(q0, fmaxf(q1, q2));
    float e0 = expf(q0 - m), e1 = expf(q1 - m), e2 = expf(q2 - m);
    float inv = 1.0f / (e0 + e1 + e2);
    outp[192 + b * 3 + 0] = e0 * inv;
    outp[192 + b * 3 + 1] = e1 * inv;
    outp[192 + b * 3 + 2] = e2 * inv;
  }
}

extern "C" void kernel_launch(void* const* d_in, const int* in_sizes, int n_in,
                              void* d_out, int out_size, void* d_ws, size_t ws_size,
                              hipStream_t stream) {
  const float* seq   = (const float*)d_in[0];
  const float* adj   = (const float*)d_in[1];
  const int*   amask = (const int*)d_in[2];
  const float* ln_a  = (const float*)d_in[3];
  const float* ln_b  = (const float*)d_in[4];
  const float* asp_w = (const float*)d_in[5];
  const float* asp_b = (const float*)d_in[6];
  const float* W0    = (const float*)d_in[7];
  const float* b0    = (const float*)d_in[8];
  const float* W1    = (const float*)d_in[9];
  const float* b1    = (const float*)d_in[10];
  const float* W2    = (const float*)d_in[11];
  const float* b2    = (const float*)d_in[12];
  const float* cls_w = (const float*)d_in[13];
  const float* cls_b = (const float*)d_in[14];
  float* out = (float*)d_out;

  char* w = (char*)d_ws;
  bf16* P             = (bf16*)w;           w += (size_t)NROWS * MDIM * 2;  // 32 MB
  bf16* xn            = (bf16*)w;           w += (size_t)NROWS * DDIM * 2;  // 64 MB
  bf16* outb          = (bf16*)w;           w += (size_t)NROWS * MDIM * 2;  // 32 MB
  unsigned short* nbr = (unsigned short*)w; w += (size_t)NROWS * 512 * 2;   // 32 MB
  int* cnt            = (int*)w;            w += (size_t)NROWS * 4;
  float* denomv       = (float*)w;          w += (size_t)NROWS * 4;
  float* loss_arr     = (float*)w;          w += (size_t)NROWS * 4;
  float* part         = (float*)w;          w += (size_t)4096 * 1024 * 4;   // 16 MB
  bf16* W0T           = (bf16*)w;           w += (size_t)512 * 1024 * 2;
  bf16* W1T           = (bf16*)w;           w += (size_t)512 * 512 * 2;
  bf16* W2T           = (bf16*)w;           w += (size_t)512 * 512 * 2;

  // 1. fused prep: ln_head | build_nbr | wcast (nt hints on streams)
  prep_kernel<<<16640, 256, 0, stream>>>(seq, adj, amask, ln_a, ln_b, asp_w,
                                         asp_b, W0, W1, W2, xn, out + 384,
                                         loss_arr, nbr, cnt, denomv, W0T, W1T,
                                         W2T);
  // 2-7. GCN layers: P = in @ W (MFMA), then sparse agg + bias/denom/relu.
  // Layer 3's agg is fused with the pooling partial sums (no outb write).
  gemm256<<<256, 512, 0, stream>>>(xn, W0T, P, 1024);
  agg_kernel<<<4096, 128, 0, stream>>>(P, nbr, cnt, denomv, b0, outb);
  gemm256<<<256, 512, 0, stream>>>(outb, W1T, P, 512);
  agg_kernel<<<4096, 128, 0, stream>>>(P, nbr, cnt, denomv, b1, outb);
  gemm256<<<256, 512, 0, stream>>>(outb, W2T, P, 512);
  agg_pool_kernel<<<4096, 128, 0, stream>>>(P, nbr, cnt, denomv, b2, amask,
                                            part);
  // 8. pool finish + classifier + softmax (+ loss)
  poolcls_kernel<<<65, 512, 0, stream>>>(part, amask, loss_arr, cls_w, cls_b,
                                         out);
}